// Round 10
// baseline (591.849 us; speedup 1.0000x reference)
//
#include <hip/hip_runtime.h>
#include <hip/hip_cooperative_groups.h>
#include <math.h>

namespace cg = cooperative_groups;

#define N_NODES 50000
#define N_EDGES 600000
#define D 128
#define TWO_D 256
#define BN_EPS 1e-5f
#define LN_EPS 1e-5f
#define LOG2E 1.44269504f
#define TILES 3125      // 50000 / 16 exact

typedef __attribute__((ext_vector_type(8))) short short8;
typedef __attribute__((ext_vector_type(4))) float f32x4;

static __device__ __forceinline__ unsigned short f2b(float f) {
    unsigned int u = __builtin_bit_cast(unsigned int, f);
    u = u + 0x7fffu + ((u >> 16) & 1u);   // RNE
    return (unsigned short)(u >> 16);
}
static __device__ __forceinline__ float b2f(unsigned short s) {
    unsigned int u = ((unsigned int)s) << 16;
    return __builtin_bit_cast(float, u);
}
static __device__ __forceinline__ float lo_f(unsigned int p) {
    return __builtin_bit_cast(float, p << 16);
}
static __device__ __forceinline__ float hi_f(unsigned int p) {
    return __builtin_bit_cast(float, p & 0xffff0000u);
}

struct Params {
    const float* x; const int* src; const int* dst; const float* t_ptr;
    const float* W1; const float* b1; const float* bn_g; const float* bn_b;
    const float* W2; const float* b2; const float* ln_g; const float* ln_b;
    int* counts; int* offsets; int* rank; int* csr_src;
    unsigned int* xb2; unsigned int* h0b2; unsigned short* h1b;
    unsigned short* W1t; unsigned short* W2t;
    float* partial_s; float* partial_ss; float* bnacc;
    float* out; int nblk;
};

struct SmemScan { int buf[256]; };
struct SmemG1 { float red_s[4][256]; float red_ss[4][256]; };
struct SmemG2 {
    float sc_s[TWO_D], sh_s[TWO_D];
    unsigned short As[16][264];
    float yt[16][132];
    float mu_s[16], rstd_s[16];
};
union SmemAll { SmemScan sc; SmemG1 g1; SmemG2 g2; };

__global__ __launch_bounds__(256, 3) void mega(Params p) {
    cg::grid_group grid = cg::this_grid();
    __shared__ SmemAll sm;
    int tid = threadIdx.x;
    int bid = blockIdx.x;
    int T = p.nblk * 256;
    int g = bid * 256 + tid;

    // ---- P0: zero counts + bnacc ----
    for (int i = g; i < N_NODES; i += T) p.counts[i] = 0;
    if (g < 2 * TWO_D) p.bnacc[g] = 0.f;
    grid.sync();

    // ---- P1: prep (x->bf16 packed, W->bf16 transposed, count+rank) ----
    for (int i = g; i < N_NODES * 64; i += T) {
        float2 v = ((const float2*)p.x)[i];
        p.xb2[i] = (unsigned int)f2b(v.x) | ((unsigned int)f2b(v.y) << 16);
    }
    for (int i = g; i < 32768; i += T) {
        int n = i >> 7, k = i & 127;
        p.W1t[i] = f2b(p.W1[k * 256 + n]);          // W1t[n][k] = W1[k][n]
    }
    for (int i = g; i < 32768; i += T) {
        int n = i >> 8, k = i & 255;
        p.W2t[i] = f2b(p.W2[k * 128 + n]);          // W2t[n][k] = W2[k][n]
    }
    for (int i = g; i < N_EDGES; i += T) p.rank[i] = atomicAdd(&p.counts[p.dst[i]], 1);
    grid.sync();

    // ---- P2: exclusive scan -> offsets (blocks 0..195, redundant-prefix) ----
    if (bid < 196) {
        int start = bid * 256;
        int part = 0;
        for (int j2 = tid; j2 < start; j2 += 256) part += p.counts[j2];
        sm.sc.buf[tid] = part;
        __syncthreads();
        for (int off = 128; off > 0; off >>= 1) {
            if (tid < off) sm.sc.buf[tid] += sm.sc.buf[tid + off];
            __syncthreads();
        }
        int base = sm.sc.buf[0];
        __syncthreads();
        int i = start + tid;
        int v = (i < N_NODES) ? p.counts[i] : 0;
        sm.sc.buf[tid] = v;
        __syncthreads();
        for (int off = 1; off < 256; off <<= 1) {
            int t2 = (tid >= off) ? sm.sc.buf[tid - off] : 0;
            __syncthreads();
            sm.sc.buf[tid] += t2;
            __syncthreads();
        }
        if (i < N_NODES) p.offsets[i + 1] = base + sm.sc.buf[tid];
        if (i == 0) p.offsets[0] = 0;
    }
    grid.sync();

    // ---- P3: scatter (atomic-free) ----
    for (int i = g; i < N_EDGES; i += T)
        p.csr_src[p.offsets[p.dst[i]] + p.rank[i]] = p.src[i];
    grid.sync();

    // ---- P4: softmax aggregation (1 wave/node, scalar index feed, unroll-4) ----
    {
        int wq = __builtin_amdgcn_readfirstlane((int)(tid >> 6));
        int lane = tid & 63;
        int wavesTotal = p.nblk * 4;
        float tl = p.t_ptr[0] * LOG2E;
        for (int node = bid * 4 + wq; node < N_NODES; node += wavesTotal) {
            int beg = p.offsets[node], end = p.offsets[node + 1];
            float s0 = 0.f, s1 = 0.f, m0 = 0.f, m1 = 0.f;
            float s0b = 0.f, s1b = 0.f, m0b = 0.f, m1b = 0.f;
            int j = beg;
            for (; j + 4 <= end; j += 4) {
                int sa = __builtin_amdgcn_readfirstlane(p.csr_src[j]);
                int sb = __builtin_amdgcn_readfirstlane(p.csr_src[j + 1]);
                int sc = __builtin_amdgcn_readfirstlane(p.csr_src[j + 2]);
                int sd = __builtin_amdgcn_readfirstlane(p.csr_src[j + 3]);
                unsigned int pa = p.xb2[sa * 64 + lane];
                unsigned int pb = p.xb2[sb * 64 + lane];
                unsigned int pc = p.xb2[sc * 64 + lane];
                unsigned int pd = p.xb2[sd * 64 + lane];
                float ma0 = fmaxf(lo_f(pa), 0.f), ma1 = fmaxf(hi_f(pa), 0.f);
                float mb0 = fmaxf(lo_f(pb), 0.f), mb1 = fmaxf(hi_f(pb), 0.f);
                float mc0 = fmaxf(lo_f(pc), 0.f), mc1 = fmaxf(hi_f(pc), 0.f);
                float md0 = fmaxf(lo_f(pd), 0.f), md1 = fmaxf(hi_f(pd), 0.f);
                float ea0 = exp2f(ma0 * tl), ea1 = exp2f(ma1 * tl);
                float eb0 = exp2f(mb0 * tl), eb1 = exp2f(mb1 * tl);
                float ec0 = exp2f(mc0 * tl), ec1 = exp2f(mc1 * tl);
                float ed0 = exp2f(md0 * tl), ed1 = exp2f(md1 * tl);
                s0  += ea0; m0  = fmaf(ea0, ma0, m0);
                s1  += ea1; m1  = fmaf(ea1, ma1, m1);
                s0b += eb0; m0b = fmaf(eb0, mb0, m0b);
                s1b += eb1; m1b = fmaf(eb1, mb1, m1b);
                s0  += ec0; m0  = fmaf(ec0, mc0, m0);
                s1  += ec1; m1  = fmaf(ec1, mc1, m1);
                s0b += ed0; m0b = fmaf(ed0, md0, m0b);
                s1b += ed1; m1b = fmaf(ed1, md1, m1b);
            }
            for (; j < end; ++j) {
                int sa = __builtin_amdgcn_readfirstlane(p.csr_src[j]);
                unsigned int pa = p.xb2[sa * 64 + lane];
                float ma0 = fmaxf(lo_f(pa), 0.f), ma1 = fmaxf(hi_f(pa), 0.f);
                float ea0 = exp2f(ma0 * tl), ea1 = exp2f(ma1 * tl);
                s0 += ea0; m0 = fmaf(ea0, ma0, m0);
                s1 += ea1; m1 = fmaf(ea1, ma1, m1);
            }
            float agg0 = (m0 + m0b) / (s0 + s0b + 1e-16f);
            float agg1 = (m1 + m1b) / (s1 + s1b + 1e-16f);
            unsigned int px = p.xb2[node * 64 + lane];
            p.h0b2[node * 64 + lane] = (unsigned int)f2b(agg0 + lo_f(px)) |
                                       ((unsigned int)f2b(agg1 + hi_f(px)) << 16);
        }
    }
    grid.sync();

    // ---- P5: GEMM1 (persistent B, M-loop) + BN partials ----
    {
        const unsigned short* h0b = (const unsigned short*)p.h0b2;
        int wave = tid >> 6;
        int quad = (tid >> 4) & 3, m16 = tid & 15;
        int col0 = wave * 64;
        short8 bfr[4][4];
        float bias[4];
#pragma unroll
        for (int f = 0; f < 4; ++f) {
            bias[f] = p.b1[col0 + f * 16 + m16];
#pragma unroll
            for (int kk = 0; kk < 4; ++kk)
                bfr[kk][f] = *(const short8*)(p.W1t + (col0 + f * 16 + m16) * D + kk * 32 + quad * 8);
        }
        float ps[4] = {0.f, 0.f, 0.f, 0.f}, pss[4] = {0.f, 0.f, 0.f, 0.f};
        for (int it = bid; it < TILES; it += p.nblk) {
            int row0 = it * 16;
            const short8* aptr = (const short8*)(h0b + (row0 + m16) * D + quad * 8);
            short8 afr[4];
#pragma unroll
            for (int kk = 0; kk < 4; ++kk) afr[kk] = aptr[kk * 4];
            f32x4 acc[4];
#pragma unroll
            for (int f = 0; f < 4; ++f) acc[f] = (f32x4){0.f, 0.f, 0.f, 0.f};
#pragma unroll
            for (int kk = 0; kk < 4; ++kk)
#pragma unroll
                for (int f = 0; f < 4; ++f)
                    acc[f] = __builtin_amdgcn_mfma_f32_16x16x32_bf16(afr[kk], bfr[kk][f], acc[f], 0, 0, 0);
#pragma unroll
            for (int f = 0; f < 4; ++f) {
                int col = col0 + f * 16 + m16;
#pragma unroll
                for (int r = 0; r < 4; ++r) {
                    float v = acc[f][r] + bias[f];
                    p.h1b[(row0 + quad * 4 + r) * TWO_D + col] = f2b(v);
                    ps[f] += v;
                    pss[f] += v * v;
                }
            }
        }
#pragma unroll
        for (int f = 0; f < 4; ++f) {
            float s = ps[f], ss = pss[f];
            s += __shfl_xor(s, 16);  s += __shfl_xor(s, 32);
            ss += __shfl_xor(ss, 16); ss += __shfl_xor(ss, 32);
            if (quad == 0) {
                sm.g1.red_s[wave][col0 + f * 16 + m16] = s;
                sm.g1.red_ss[wave][col0 + f * 16 + m16] = ss;
            }
        }
        __syncthreads();
        int base2 = bid * 256 + tid;
        p.partial_s[base2]  = sm.g1.red_s[0][tid] + sm.g1.red_s[1][tid] +
                              sm.g1.red_s[2][tid] + sm.g1.red_s[3][tid];
        p.partial_ss[base2] = sm.g1.red_ss[0][tid] + sm.g1.red_ss[1][tid] +
                              sm.g1.red_ss[2][tid] + sm.g1.red_ss[3][tid];
    }
    grid.sync();

    // ---- P6: BN reduce (blocks 0..63, 64 atomics/address) ----
    if (bid < 64) {
        float s = 0.f, ss = 0.f;
        for (int rb = bid; rb < p.nblk; rb += 64) {
            s += p.partial_s[rb * 256 + tid];
            ss += p.partial_ss[rb * 256 + tid];
        }
        atomicAdd(&p.bnacc[tid], s);
        atomicAdd(&p.bnacc[TWO_D + tid], ss);
    }
    grid.sync();

    // ---- P7: GEMM2 (persistent B, M-loop): BN finalize + BN/ReLU stage + LN + mix + residual ----
    {
        int wave = tid >> 6;
        int quad = (tid >> 4) & 3, m16 = tid & 15;
        {   // BN finalize per block
            float mean = p.bnacc[tid] * (1.f / N_NODES);
            float var = p.bnacc[TWO_D + tid] * (1.f / N_NODES) - mean * mean;
            float sc = p.bn_g[tid] * rsqrtf(var + BN_EPS);
            sm.g2.sc_s[tid] = sc;
            sm.g2.sh_s[tid] = p.bn_b[tid] - mean * sc;
        }
        short8 bfr[8][2];
        float bias[2];
#pragma unroll
        for (int f = 0; f < 2; ++f) {
            int col = wave * 32 + f * 16 + m16;
            bias[f] = p.b2[col];
#pragma unroll
            for (int kk = 0; kk < 8; ++kk)
                bfr[kk][f] = *(const short8*)(p.W2t + col * TWO_D + kk * 32 + quad * 8);
        }
        int cp = tid & 63, rg = tid >> 6;
        float lg0 = p.ln_g[2 * cp], lg1 = p.ln_g[2 * cp + 1];
        float lb0 = p.ln_b[2 * cp], lb1 = p.ln_b[2 * cp + 1];
        int sr = tid >> 4, sc0 = (tid & 15) * 16;
        __syncthreads();

        for (int it = bid; it < TILES; it += p.nblk) {
            int row0 = it * 16;
            {   // stage BN+ReLU'd A tile
                const unsigned short* srcp = p.h1b + (row0 + sr) * TWO_D + sc0;
                short8 v0 = *(const short8*)(srcp);
                short8 v1 = *(const short8*)(srcp + 8);
                short8 o0, o1;
#pragma unroll
                for (int jj = 0; jj < 8; ++jj) {
                    float v = b2f((unsigned short)v0[jj]);
                    v = fmaxf(v * sm.g2.sc_s[sc0 + jj] + sm.g2.sh_s[sc0 + jj], 0.f);
                    o0[jj] = (short)f2b(v);
                    float w = b2f((unsigned short)v1[jj]);
                    w = fmaxf(w * sm.g2.sc_s[sc0 + 8 + jj] + sm.g2.sh_s[sc0 + 8 + jj], 0.f);
                    o1[jj] = (short)f2b(w);
                }
                *(short8*)&sm.g2.As[sr][sc0] = o0;
                *(short8*)&sm.g2.As[sr][sc0 + 8] = o1;
            }
            __syncthreads();
            f32x4 acc[2] = {{0.f,0.f,0.f,0.f},{0.f,0.f,0.f,0.f}};
#pragma unroll
            for (int kk = 0; kk < 8; ++kk) {
                short8 a = *(const short8*)&sm.g2.As[m16][kk * 32 + quad * 8];
#pragma unroll
                for (int f = 0; f < 2; ++f)
                    acc[f] = __builtin_amdgcn_mfma_f32_16x16x32_bf16(a, bfr[kk][f], acc[f], 0, 0, 0);
            }
#pragma unroll
            for (int f = 0; f < 2; ++f) {
                int col = wave * 32 + f * 16 + m16;
#pragma unroll
                for (int r = 0; r < 4; ++r) sm.g2.yt[quad * 4 + r][col] = acc[f][r] + bias[f];
            }
            __syncthreads();
            {   // LN stats: 16 threads per row
                int r = tid >> 4, lane16 = tid & 15;
                float s = 0.f, ss = 0.f;
                for (int jj = lane16; jj < D; jj += 16) {
                    float v = sm.g2.yt[r][jj];
                    s += v;
                    ss += v * v;
                }
#pragma unroll
                for (int o = 1; o < 16; o <<= 1) {
                    s += __shfl_xor(s, o);
                    ss += __shfl_xor(ss, o);
                }
                if (lane16 == 0) {
                    float mu = s * (1.f / D);
                    float var = ss * (1.f / D) - mu * mu;
                    sm.g2.mu_s[r] = mu;
                    sm.g2.rstd_s[r] = rsqrtf(var + LN_EPS);
                }
            }
            __syncthreads();
#pragma unroll
            for (int rp = 0; rp < 4; ++rp) {
                int rl = rp * 4 + rg;
                int row = row0 + rl;
                unsigned int px = p.xb2[row * 64 + cp];
                float z0 = (sm.g2.yt[rl][2 * cp] - sm.g2.mu_s[rl]) * sm.g2.rstd_s[rl] * lg0 + lb0;
                float z1 = (sm.g2.yt[rl][2 * cp + 1] - sm.g2.mu_s[rl]) * sm.g2.rstd_s[rl] * lg1 + lb1;
                float o0 = 0.5f * lo_f(px) + 0.5f * fmaxf(z0, 0.f) + 0.5f * z0;
                float o1 = 0.5f * hi_f(px) + 0.5f * fmaxf(z1, 0.f) + 0.5f * z1;
                ((float2*)p.out)[row * 64 + cp] = make_float2(o0, o1);
            }
            __syncthreads();   // protect As/yt before next tile's staging writes
        }
    }
}

// ---------------- launch ----------------

extern "C" void kernel_launch(void* const* d_in, const int* in_sizes, int n_in,
                              void* d_out, int out_size, void* d_ws, size_t ws_size,
                              hipStream_t stream) {
    char* ws = (char*)d_ws;
    size_t off = 0;
    auto alloc = [&](size_t bytes) -> void* {
        void* p = ws + off;
        off = (off + bytes + 255) & ~(size_t)255;
        return p;
    };
    Params p;
    p.x    = (const float*)d_in[0];
    const int* ei = (const int*)d_in[1];
    p.src  = ei;
    p.dst  = ei + N_EDGES;
    p.t_ptr = (const float*)d_in[2];
    p.W1   = (const float*)d_in[3];
    p.b1   = (const float*)d_in[4];
    p.bn_g = (const float*)d_in[5];
    p.bn_b = (const float*)d_in[6];
    p.W2   = (const float*)d_in[7];
    p.b2   = (const float*)d_in[8];
    p.ln_g = (const float*)d_in[9];
    p.ln_b = (const float*)d_in[10];
    p.out  = (float*)d_out;

    p.counts     = (int*)alloc((size_t)N_NODES * 4);
    p.offsets    = (int*)alloc((size_t)(N_NODES + 1) * 4);
    p.rank       = (int*)alloc((size_t)N_EDGES * 4);
    p.csr_src    = (int*)alloc((size_t)N_EDGES * 4);
    p.xb2        = (unsigned int*)alloc((size_t)N_NODES * 64 * 4);
    p.h0b2       = (unsigned int*)alloc((size_t)N_NODES * 64 * 4);
    p.h1b        = (unsigned short*)alloc((size_t)N_NODES * TWO_D * 2);
    p.W1t        = (unsigned short*)alloc((size_t)D * TWO_D * 2);
    p.W2t        = (unsigned short*)alloc((size_t)D * TWO_D * 2);
    p.partial_s  = (float*)alloc((size_t)1024 * TWO_D * 4);
    p.partial_ss = (float*)alloc((size_t)1024 * TWO_D * 4);
    p.bnacc      = (float*)alloc(2 * TWO_D * 4);

    int perCU = 0;
    hipError_t e = hipOccupancyMaxActiveBlocksPerMultiprocessor(&perCU, mega, 256, 0);
    if (e != hipSuccess || perCU < 1) perCU = 2;
    int nblk = perCU * 256;          // 256 CUs on MI355X
    if (nblk > 1024) nblk = 1024;
    p.nblk = nblk;

    void* kargs[] = { &p };
    hipLaunchCooperativeKernel((const void*)mega, dim3(nblk), dim3(256), kargs, 0, stream);
}

// Round 12
// 295.209 us; speedup vs baseline: 2.0048x; 2.0048x over previous
//
#include <hip/hip_runtime.h>
#include <math.h>

#define N_NODES 50000
#define N_EDGES 600000
#define D 128
#define TWO_D 256
#define BN_EPS 1e-5f
#define LN_EPS 1e-5f
#define LOG2E 1.44269504f
#define GRID_G 391      // gemm2 grid: 391 blocks x 8 tiles = 3128 >= 3125
#define TILES 3125      // 50000 / 16 exact

typedef __attribute__((ext_vector_type(8))) short short8;
typedef __attribute__((ext_vector_type(4))) float f32x4;

static __device__ __forceinline__ unsigned short f2b(float f) {
    unsigned int u = __builtin_bit_cast(unsigned int, f);
    u = u + 0x7fffu + ((u >> 16) & 1u);   // RNE
    return (unsigned short)(u >> 16);
}
static __device__ __forceinline__ float b2f(unsigned short s) {
    unsigned int u = ((unsigned int)s) << 16;
    return __builtin_bit_cast(float, u);
}
static __device__ __forceinline__ float lo_f(unsigned int p) {
    return __builtin_bit_cast(float, p << 16);
}
static __device__ __forceinline__ float hi_f(unsigned int p) {
    return __builtin_bit_cast(float, p & 0xffff0000u);
}

// ---------------- prep: x->bf16, W->bf16 transposed, zero bnacc, count+rank ----------------
// counts must be zeroed (memset) before this kernel.
__global__ __launch_bounds__(256) void prep_all(const float* __restrict__ x,
                                                const float* __restrict__ W1,
                                                const float* __restrict__ W2,
                                                const int* __restrict__ dst,
                                                unsigned short* __restrict__ W1t,
                                                unsigned short* __restrict__ W2t,
                                                unsigned int* __restrict__ xb2,
                                                int* __restrict__ counts,
                                                int* __restrict__ rank,
                                                float* __restrict__ bnacc) {
    int gid = blockIdx.x * 256 + threadIdx.x;       // grid 12500*256 = 3.2M = N*64 exact
    {
        float2 v = ((const float2*)x)[gid];
        xb2[gid] = (unsigned int)f2b(v.x) | ((unsigned int)f2b(v.y) << 16);
    }
    if (gid < 32768) {
        int n = gid >> 7, k = gid & 127;
        W1t[gid] = f2b(W1[k * 256 + n]);            // W1t[n][k] = W1[k][n]
    } else if (gid < 65536) {
        int j = gid - 32768;
        int n = j >> 8, k = j & 255;
        W2t[j] = f2b(W2[k * 128 + n]);              // W2t[n][k] = W2[k][n]
    }
    if (gid < 2 * TWO_D) bnacc[gid] = 0.f;
    if (gid < N_EDGES) rank[gid] = atomicAdd(&counts[dst[gid]], 1);
}

// ---------------- single-kernel exclusive scan: offsets[0..N] from counts ----------------
__global__ __launch_bounds__(256) void scan_offsets(const int* __restrict__ counts,
                                                    int* __restrict__ offsets) {
    __shared__ int buf[256];
    int tid = threadIdx.x;
    int start = blockIdx.x * 256;
    int part = 0;
    for (int j = tid; j < start; j += 256) part += counts[j];
    buf[tid] = part;
    __syncthreads();
    for (int off = 128; off > 0; off >>= 1) {
        if (tid < off) buf[tid] += buf[tid + off];
        __syncthreads();
    }
    int base = buf[0];
    __syncthreads();
    int i = start + tid;
    int v = (i < N_NODES) ? counts[i] : 0;
    buf[tid] = v;
    __syncthreads();
    for (int off = 1; off < 256; off <<= 1) {
        int t = (tid >= off) ? buf[tid - off] : 0;
        __syncthreads();
        buf[tid] += t;
        __syncthreads();
    }
    if (i < N_NODES) offsets[i + 1] = base + buf[tid];
    if (i == 0) offsets[0] = 0;
}

// ---------------- scatter (atomic-free: rank precomputed) ----------------
__global__ void scatter_kernel(const int* __restrict__ src, const int* __restrict__ dst,
                               const int* __restrict__ offsets, const int* __restrict__ rank,
                               int* __restrict__ csr_src) {
    int i = blockIdx.x * blockDim.x + threadIdx.x;
    if (i < N_EDGES) csr_src[offsets[dst[i]] + rank[i]] = src[i];
}

// ---------------- FUSED agg + GEMM1: one block per 16-node tile ----------------
// Waves agg 4 nodes each into LDS (h0 never touches global), then the block
// runs the persistent-B 16x256 MFMA tile. BN column partials: each column is
// owned by exactly one wave -> collapsed red_s[256] (every entry written).
__global__ __launch_bounds__(256) void agg_gemm1(const unsigned int* __restrict__ xb2,
                                                 const int* __restrict__ offsets,
                                                 const int* __restrict__ csr_src,
                                                 const float* __restrict__ t_ptr,
                                                 const unsigned short* __restrict__ W1t,
                                                 const float* __restrict__ b1,
                                                 unsigned short* __restrict__ h1b,
                                                 float* __restrict__ partial_s,
                                                 float* __restrict__ partial_ss) {
    __shared__ unsigned short As0[16][136];       // h0 tile (bf16), row stride 272B
    __shared__ float red_s[256];                  // one entry per column, fully written
    __shared__ float red_ss[256];
    int tid = threadIdx.x;
    int wave = tid >> 6, lane = tid & 63;
    int quad = lane >> 4, m16 = lane & 15;
    int col0 = wave * 64;
    int row0 = blockIdx.x * 16;                   // 3125 * 16 = 50000 exact

    // resident W1t fragments for this wave's 64 columns (loads overlap agg below)
    short8 bfr[4][4];
    float bias[4];
#pragma unroll
    for (int f = 0; f < 4; ++f) {
        bias[f] = b1[col0 + f * 16 + m16];
#pragma unroll
        for (int kk = 0; kk < 4; ++kk)
            bfr[kk][f] = *(const short8*)(W1t + (col0 + f * 16 + m16) * D + kk * 32 + quad * 8);
    }

    // ---- agg: wave handles nodes row0 + wave*4 .. +3 (2 channels/lane) ----
    float tl = t_ptr[0] * LOG2E;
#pragma unroll
    for (int i = 0; i < 4; ++i) {
        int node = row0 + wave * 4 + i;
        int beg = offsets[node], end = offsets[node + 1];
        float s0 = 0.f, s1 = 0.f, m0 = 0.f, m1 = 0.f;
        float s0b = 0.f, s1b = 0.f, m0b = 0.f, m1b = 0.f;
        int j = beg;
        for (; j + 4 <= end; j += 4) {
            int sa = __builtin_amdgcn_readfirstlane(csr_src[j]);
            int sb = __builtin_amdgcn_readfirstlane(csr_src[j + 1]);
            int sc = __builtin_amdgcn_readfirstlane(csr_src[j + 2]);
            int sd = __builtin_amdgcn_readfirstlane(csr_src[j + 3]);
            unsigned int pa = xb2[sa * 64 + lane];
            unsigned int pb = xb2[sb * 64 + lane];
            unsigned int pc = xb2[sc * 64 + lane];
            unsigned int pd = xb2[sd * 64 + lane];
            float ma0 = fmaxf(lo_f(pa), 0.f), ma1 = fmaxf(hi_f(pa), 0.f);
            float mb0 = fmaxf(lo_f(pb), 0.f), mb1 = fmaxf(hi_f(pb), 0.f);
            float mc0 = fmaxf(lo_f(pc), 0.f), mc1 = fmaxf(hi_f(pc), 0.f);
            float md0 = fmaxf(lo_f(pd), 0.f), md1 = fmaxf(hi_f(pd), 0.f);
            float ea0 = exp2f(ma0 * tl), ea1 = exp2f(ma1 * tl);
            float eb0 = exp2f(mb0 * tl), eb1 = exp2f(mb1 * tl);
            float ec0 = exp2f(mc0 * tl), ec1 = exp2f(mc1 * tl);
            float ed0 = exp2f(md0 * tl), ed1 = exp2f(md1 * tl);
            s0  += ea0; m0  = fmaf(ea0, ma0, m0);
            s1  += ea1; m1  = fmaf(ea1, ma1, m1);
            s0b += eb0; m0b = fmaf(eb0, mb0, m0b);
            s1b += eb1; m1b = fmaf(eb1, mb1, m1b);
            s0  += ec0; m0  = fmaf(ec0, mc0, m0);
            s1  += ec1; m1  = fmaf(ec1, mc1, m1);
            s0b += ed0; m0b = fmaf(ed0, md0, m0b);
            s1b += ed1; m1b = fmaf(ed1, md1, m1b);
        }
        for (; j < end; ++j) {
            int sa = __builtin_amdgcn_readfirstlane(csr_src[j]);
            unsigned int pa = xb2[sa * 64 + lane];
            float ma0 = fmaxf(lo_f(pa), 0.f), ma1 = fmaxf(hi_f(pa), 0.f);
            float ea0 = exp2f(ma0 * tl), ea1 = exp2f(ma1 * tl);
            s0 += ea0; m0 = fmaf(ea0, ma0, m0);
            s1 += ea1; m1 = fmaf(ea1, ma1, m1);
        }
        float agg0 = (m0 + m0b) / (s0 + s0b + 1e-16f);
        float agg1 = (m1 + m1b) / (s1 + s1b + 1e-16f);
        unsigned int px = xb2[node * 64 + lane];      // bf16 residual
        unsigned int packed = (unsigned int)f2b(agg0 + lo_f(px)) |
                              ((unsigned int)f2b(agg1 + hi_f(px)) << 16);
        *(unsigned int*)&As0[wave * 4 + i][lane * 2] = packed;
    }
    __syncthreads();

    // ---- GEMM1 tile: A from LDS, resident B ----
    short8 afr[4];
#pragma unroll
    for (int kk = 0; kk < 4; ++kk)
        afr[kk] = *(const short8*)&As0[m16][kk * 32 + quad * 8];
    f32x4 acc[4];
#pragma unroll
    for (int f = 0; f < 4; ++f) acc[f] = (f32x4){0.f, 0.f, 0.f, 0.f};
#pragma unroll
    for (int kk = 0; kk < 4; ++kk)
#pragma unroll
        for (int f = 0; f < 4; ++f)
            acc[f] = __builtin_amdgcn_mfma_f32_16x16x32_bf16(afr[kk], bfr[kk][f], acc[f], 0, 0, 0);

#pragma unroll
    for (int f = 0; f < 4; ++f) {
        int col = col0 + f * 16 + m16;
        float ps = 0.f, pss = 0.f;
#pragma unroll
        for (int r = 0; r < 4; ++r) {
            float v = acc[f][r] + bias[f];
            h1b[(row0 + quad * 4 + r) * TWO_D + col] = f2b(v);
            ps += v;
            pss += v * v;
        }
        ps  += __shfl_xor(ps, 16);  ps  += __shfl_xor(ps, 32);
        pss += __shfl_xor(pss, 16); pss += __shfl_xor(pss, 32);
        if (quad == 0) {              // each column written by exactly one lane
            red_s[col] = ps;
            red_ss[col] = pss;
        }
    }
    __syncthreads();
    {
        int base = blockIdx.x * 256 + tid;
        partial_s[base]  = red_s[tid];    // every entry was written above
        partial_ss[base] = red_ss[tid];
    }
}

// ---------------- BN reduce partials -> bnacc (64 atomics/address) ----------------
__global__ __launch_bounds__(256) void bn_reduce(const float* __restrict__ partial_s,
                                                 const float* __restrict__ partial_ss,
                                                 float* __restrict__ bnacc) {
    int c = threadIdx.x;
    float s = 0.f, ss = 0.f;
    for (int rb = blockIdx.x; rb < TILES; rb += 64) {
        s += partial_s[rb * 256 + c];
        ss += partial_ss[rb * 256 + c];
    }
    atomicAdd(&bnacc[c], s);
    atomicAdd(&bnacc[TWO_D + c], ss);
}

// ---------------- GEMM2 (MFMA): persistent B, M-loop; BN finalize + BN/ReLU stage + LN + mix ----------------
__global__ __launch_bounds__(256) void gemm2_mfma(const unsigned short* __restrict__ h1b,
                                                  const float* __restrict__ bnacc,
                                                  const float* __restrict__ bn_g,
                                                  const float* __restrict__ bn_b,
                                                  const unsigned short* __restrict__ W2t,
                                                  const float* __restrict__ b2,
                                                  const float* __restrict__ ln_g,
                                                  const float* __restrict__ ln_b,
                                                  const unsigned int* __restrict__ xb2,
                                                  float* __restrict__ out) {
    __shared__ float sc_s[TWO_D], sh_s[TWO_D];
    __shared__ unsigned short As[16][264];
    __shared__ float yt[16][132];
    __shared__ float mu_s[16], rstd_s[16];
    int tid = threadIdx.x;
    int wave = tid >> 6, lane = tid & 63;
    int quad = lane >> 4, m16 = lane & 15;

    {   // BN finalize per block (bnacc is 2KB, L2-resident)
        float mean = bnacc[tid] * (1.f / N_NODES);
        float var = bnacc[TWO_D + tid] * (1.f / N_NODES) - mean * mean;
        float sc = bn_g[tid] * rsqrtf(var + BN_EPS);
        sc_s[tid] = sc;
        sh_s[tid] = bn_b[tid] - mean * sc;
    }
    short8 bfr[8][2];    // resident W2t fragments
    float bias[2];
#pragma unroll
    for (int f = 0; f < 2; ++f) {
        int col = wave * 32 + f * 16 + m16;
        bias[f] = b2[col];
#pragma unroll
        for (int kk = 0; kk < 8; ++kk)
            bfr[kk][f] = *(const short8*)(W2t + col * TWO_D + kk * 32 + quad * 8);
    }
    int cp = tid & 63, rg = tid >> 6;
    float lg0 = ln_g[2 * cp], lg1 = ln_g[2 * cp + 1];
    float lb0 = ln_b[2 * cp], lb1 = ln_b[2 * cp + 1];
    int sr = tid >> 4, sc0 = (tid & 15) * 16;
    __syncthreads();

    for (int it = blockIdx.x; it < TILES; it += GRID_G) {
        int row0 = it * 16;
        {   // stage BN+ReLU'd A tile
            const unsigned short* srcp = h1b + (row0 + sr) * TWO_D + sc0;
            short8 v0 = *(const short8*)(srcp);
            short8 v1 = *(const short8*)(srcp + 8);
            short8 o0, o1;
#pragma unroll
            for (int jj = 0; jj < 8; ++jj) {
                float v = b2f((unsigned short)v0[jj]);
                v = fmaxf(v * sc_s[sc0 + jj] + sh_s[sc0 + jj], 0.f);
                o0[jj] = (short)f2b(v);
                float w = b2f((unsigned short)v1[jj]);
                w = fmaxf(w * sc_s[sc0 + 8 + jj] + sh_s[sc0 + 8 + jj], 0.f);
                o1[jj] = (short)f2b(w);
            }
            *(short8*)&As[sr][sc0] = o0;
            *(short8*)&As[sr][sc0 + 8] = o1;
        }
        __syncthreads();
        f32x4 acc[2] = {{0.f,0.f,0.f,0.f},{0.f,0.f,0.f,0.f}};
#pragma unroll
        for (int kk = 0; kk < 8; ++kk) {
            short8 a = *(const short8*)&As[m16][kk * 32 + quad * 8];
#pragma unroll
            for (int f = 0; f < 2; ++f)
                acc[f] = __builtin_amdgcn_mfma_f32_16x16x32_bf16(a, bfr[kk][f], acc[f], 0, 0, 0);
        }
#pragma unroll
        for (int f = 0; f < 2; ++f) {
            int col = wave * 32 + f * 16 + m16;
#pragma unroll
            for (int r = 0; r < 4; ++r) yt[quad * 4 + r][col] = acc[f][r] + bias[f];
        }
        __syncthreads();
        {   // LN stats: 16 threads per row
            int r = tid >> 4, lane16 = tid & 15;
            float s = 0.f, ss = 0.f;
            for (int jj = lane16; jj < D; jj += 16) {
                float v = yt[r][jj];
                s += v;
                ss += v * v;
            }
#pragma unroll
            for (int o = 1; o < 16; o <<= 1) {
                s += __shfl_xor(s, o);
                ss += __shfl_xor(ss, o);
            }
            if (lane16 == 0) {
                float mu = s * (1.f / D);
                float var = ss * (1.f / D) - mu * mu;
                mu_s[r] = mu;
                rstd_s[r] = rsqrtf(var + LN_EPS);
            }
        }
        __syncthreads();
#pragma unroll
        for (int rp = 0; rp < 4; ++rp) {
            int rl = rp * 4 + rg;
            int row = row0 + rl;
            unsigned int px = xb2[row * 64 + cp];
            float z0 = (yt[rl][2 * cp] - mu_s[rl]) * rstd_s[rl] * lg0 + lb0;
            float z1 = (yt[rl][2 * cp + 1] - mu_s[rl]) * rstd_s[rl] * lg1 + lb1;
            float o0 = 0.5f * lo_f(px) + 0.5f * fmaxf(z0, 0.f) + 0.5f * z0;
            float o1 = 0.5f * hi_f(px) + 0.5f * fmaxf(z1, 0.f) + 0.5f * z1;
            ((float2*)out)[row * 64 + cp] = make_float2(o0, o1);
        }
        __syncthreads();   // protect As/yt before next tile's staging writes
    }
}

// ---------------- launch ----------------

extern "C" void kernel_launch(void* const* d_in, const int* in_sizes, int n_in,
                              void* d_out, int out_size, void* d_ws, size_t ws_size,
                              hipStream_t stream) {
    const float* x    = (const float*)d_in[0];
    const int*   ei   = (const int*)d_in[1];
    const float* t    = (const float*)d_in[2];
    const float* W1   = (const float*)d_in[3];
    const float* b1   = (const float*)d_in[4];
    const float* bn_g = (const float*)d_in[5];
    const float* bn_b = (const float*)d_in[6];
    const float* W2   = (const float*)d_in[7];
    const float* b2   = (const float*)d_in[8];
    const float* ln_g = (const float*)d_in[9];
    const float* ln_b = (const float*)d_in[10];
    float* out = (float*)d_out;

    char* ws = (char*)d_ws;
    size_t off = 0;
    auto alloc = [&](size_t bytes) -> void* {
        void* p = ws + off;
        off = (off + bytes + 255) & ~(size_t)255;
        return p;
    };
    int*            counts     = (int*)alloc((size_t)N_NODES * 4);
    int*            offsets    = (int*)alloc((size_t)(N_NODES + 1) * 4);
    int*            rank       = (int*)alloc((size_t)N_EDGES * 4);
    int*            csr_src    = (int*)alloc((size_t)N_EDGES * 4);
    unsigned int*   xb2        = (unsigned int*)alloc((size_t)N_NODES * 64 * 4);
    unsigned short* h1b        = (unsigned short*)alloc((size_t)N_NODES * TWO_D * 2);
    unsigned short* W1t        = (unsigned short*)alloc((size_t)D * TWO_D * 2);
    unsigned short* W2t        = (unsigned short*)alloc((size_t)D * TWO_D * 2);
    float*          partial_s  = (float*)alloc((size_t)TILES * TWO_D * 4);
    float*          partial_ss = (float*)alloc((size_t)TILES * TWO_D * 4);
    float*          bnacc      = (float*)alloc(2 * TWO_D * 4);

    const int* src = ei;
    const int* dst = ei + N_EDGES;

    hipMemsetAsync(counts, 0, (size_t)N_NODES * 4, stream);
    prep_all<<<12500, 256, 0, stream>>>(x, W1, W2, dst, W1t, W2t, xb2, counts, rank, bnacc);
    scan_offsets<<<196, 256, 0, stream>>>(counts, offsets);
    scatter_kernel<<<(N_EDGES + 255) / 256, 256, 0, stream>>>(src, dst, offsets, rank, csr_src);
    agg_gemm1<<<TILES, 256, 0, stream>>>(xb2, offsets, csr_src, t, W1t, b1, h1b,
                                         partial_s, partial_ss);
    bn_reduce<<<64, 256, 0, stream>>>(partial_s, partial_ss, bnacc);
    gemm2_mfma<<<GRID_G, 256, 0, stream>>>(h1b, bnacc, bn_g, bn_b, W2t, b2,
                                           ln_g, ln_b, xb2, out);
}

// Round 13
// 245.075 us; speedup vs baseline: 2.4150x; 1.2046x over previous
//
#include <hip/hip_runtime.h>
#include <math.h>

#define N_NODES 50000
#define N_EDGES 600000
#define D 128
#define TWO_D 256
#define BN_EPS 1e-5f
#define LN_EPS 1e-5f
#define LOG2E 1.44269504f
#define GRID_G 782      // GEMM grids: 782 blocks x 4 tiles = 3128 >= 3125
#define TILES 3125      // 50000 / 16 exact

typedef __attribute__((ext_vector_type(8))) short short8;
typedef __attribute__((ext_vector_type(4))) float f32x4;

static __device__ __forceinline__ unsigned short f2b(float f) {
    unsigned int u = __builtin_bit_cast(unsigned int, f);
    u = u + 0x7fffu + ((u >> 16) & 1u);   // RNE
    return (unsigned short)(u >> 16);
}
static __device__ __forceinline__ float b2f(unsigned short s) {
    unsigned int u = ((unsigned int)s) << 16;
    return __builtin_bit_cast(float, u);
}
static __device__ __forceinline__ float lo_f(unsigned int p) {
    return __builtin_bit_cast(float, p << 16);
}
static __device__ __forceinline__ float hi_f(unsigned int p) {
    return __builtin_bit_cast(float, p & 0xffff0000u);
}

// ---------------- prep: x->bf16, W->bf16 transposed, zero bnacc, count+rank ----------------
// counts must be zeroed (memset) before this kernel.
__global__ __launch_bounds__(256) void prep_all(const float* __restrict__ x,
                                                const float* __restrict__ W1,
                                                const float* __restrict__ W2,
                                                const int* __restrict__ dst,
                                                unsigned short* __restrict__ W1t,
                                                unsigned short* __restrict__ W2t,
                                                unsigned int* __restrict__ xb2,
                                                int* __restrict__ counts,
                                                int* __restrict__ rank,
                                                float* __restrict__ bnacc) {
    int gid = blockIdx.x * 256 + threadIdx.x;       // grid 12500*256 = 3.2M = N*64 exact
    {
        float2 v = ((const float2*)x)[gid];
        xb2[gid] = (unsigned int)f2b(v.x) | ((unsigned int)f2b(v.y) << 16);
    }
    if (gid < 32768) {
        int n = gid >> 7, k = gid & 127;
        W1t[gid] = f2b(W1[k * 256 + n]);            // W1t[n][k] = W1[k][n]
    } else if (gid < 65536) {
        int j = gid - 32768;
        int n = j >> 8, k = j & 255;
        W2t[j] = f2b(W2[k * 128 + n]);              // W2t[n][k] = W2[k][n]
    }
    if (gid < 2 * TWO_D) bnacc[gid] = 0.f;
    if (gid < N_EDGES) rank[gid] = atomicAdd(&counts[dst[gid]], 1);
}

// ---------------- single-kernel exclusive scan: offsets[0..N] from counts ----------------
__global__ __launch_bounds__(256) void scan_offsets(const int* __restrict__ counts,
                                                    int* __restrict__ offsets) {
    __shared__ int buf[256];
    int tid = threadIdx.x;
    int start = blockIdx.x * 256;
    int part = 0;
    for (int j = tid; j < start; j += 256) part += counts[j];
    buf[tid] = part;
    __syncthreads();
    for (int off = 128; off > 0; off >>= 1) {
        if (tid < off) buf[tid] += buf[tid + off];
        __syncthreads();
    }
    int base = buf[0];
    __syncthreads();
    int i = start + tid;
    int v = (i < N_NODES) ? counts[i] : 0;
    buf[tid] = v;
    __syncthreads();
    for (int off = 1; off < 256; off <<= 1) {
        int t = (tid >= off) ? buf[tid - off] : 0;
        __syncthreads();
        buf[tid] += t;
        __syncthreads();
    }
    if (i < N_NODES) offsets[i + 1] = base + buf[tid];
    if (i == 0) offsets[0] = 0;
}

// ---------------- scatter (atomic-free: rank precomputed) ----------------
__global__ void scatter_kernel(const int* __restrict__ src, const int* __restrict__ dst,
                               const int* __restrict__ offsets, const int* __restrict__ rank,
                               int* __restrict__ csr_src) {
    int i = blockIdx.x * blockDim.x + threadIdx.x;
    if (i < N_EDGES) csr_src[offsets[dst[i]] + rank[i]] = src[i];
}

// ---------------- softmax aggregation: 1 wave/node, scalar index feed, unroll-4 ----------------
// 50000 independent waves, no block barriers -> degree skew self-balances.
__global__ __launch_bounds__(256) void agg_kernel(const unsigned int* __restrict__ xb2,
                                                  const int* __restrict__ offsets,
                                                  const int* __restrict__ csr_src,
                                                  const float* __restrict__ t_ptr,
                                                  unsigned int* __restrict__ h0b2) {
    int wq = __builtin_amdgcn_readfirstlane((int)(threadIdx.x >> 6));  // wave id, SGPR
    int node = blockIdx.x * 4 + wq;                   // SGPR
    int lane = threadIdx.x & 63;                      // 2 channels per lane
    int beg = offsets[node], end = offsets[node + 1]; // s_load
    float tl = t_ptr[0] * LOG2E;
    float s0 = 0.f, s1 = 0.f, m0 = 0.f, m1 = 0.f;
    float s0b = 0.f, s1b = 0.f, m0b = 0.f, m1b = 0.f;
    int j = beg;
    for (; j + 4 <= end; j += 4) {
        int sa = __builtin_amdgcn_readfirstlane(csr_src[j]);       // 4 independent s_loads
        int sb = __builtin_amdgcn_readfirstlane(csr_src[j + 1]);
        int sc = __builtin_amdgcn_readfirstlane(csr_src[j + 2]);
        int sd = __builtin_amdgcn_readfirstlane(csr_src[j + 3]);
        unsigned int pa = xb2[sa * 64 + lane];        // 4 gathers in flight
        unsigned int pb = xb2[sb * 64 + lane];
        unsigned int pc = xb2[sc * 64 + lane];
        unsigned int pd = xb2[sd * 64 + lane];
        float ma0 = fmaxf(lo_f(pa), 0.f), ma1 = fmaxf(hi_f(pa), 0.f);
        float mb0 = fmaxf(lo_f(pb), 0.f), mb1 = fmaxf(hi_f(pb), 0.f);
        float mc0 = fmaxf(lo_f(pc), 0.f), mc1 = fmaxf(hi_f(pc), 0.f);
        float md0 = fmaxf(lo_f(pd), 0.f), md1 = fmaxf(hi_f(pd), 0.f);
        float ea0 = exp2f(ma0 * tl), ea1 = exp2f(ma1 * tl);
        float eb0 = exp2f(mb0 * tl), eb1 = exp2f(mb1 * tl);
        float ec0 = exp2f(mc0 * tl), ec1 = exp2f(mc1 * tl);
        float ed0 = exp2f(md0 * tl), ed1 = exp2f(md1 * tl);
        s0  += ea0; m0  = fmaf(ea0, ma0, m0);
        s1  += ea1; m1  = fmaf(ea1, ma1, m1);
        s0b += eb0; m0b = fmaf(eb0, mb0, m0b);
        s1b += eb1; m1b = fmaf(eb1, mb1, m1b);
        s0  += ec0; m0  = fmaf(ec0, mc0, m0);
        s1  += ec1; m1  = fmaf(ec1, mc1, m1);
        s0b += ed0; m0b = fmaf(ed0, md0, m0b);
        s1b += ed1; m1b = fmaf(ed1, md1, m1b);
    }
    for (; j < end; ++j) {
        int sa = __builtin_amdgcn_readfirstlane(csr_src[j]);
        unsigned int pa = xb2[sa * 64 + lane];
        float ma0 = fmaxf(lo_f(pa), 0.f), ma1 = fmaxf(hi_f(pa), 0.f);
        float ea0 = exp2f(ma0 * tl), ea1 = exp2f(ma1 * tl);
        s0 += ea0; m0 = fmaf(ea0, ma0, m0);
        s1 += ea1; m1 = fmaf(ea1, ma1, m1);
    }
    float agg0 = (m0 + m0b) / (s0 + s0b + 1e-16f);
    float agg1 = (m1 + m1b) / (s1 + s1b + 1e-16f);
    unsigned int px = xb2[node * 64 + lane];          // bf16 residual
    h0b2[node * 64 + lane] = (unsigned int)f2b(agg0 + lo_f(px)) |
                             ((unsigned int)f2b(agg1 + hi_f(px)) << 16);
}

// ---------------- GEMM1 (MFMA): persistent B in registers, M-loop ----------------
// 782 blocks x 4 waves; wave w owns cols w*64..+63. BN partials: each column
// owned by exactly one wave -> red_s[256], every entry written before read.
__global__ __launch_bounds__(256) void gemm1_mfma(const unsigned short* __restrict__ h0b,
                                                  const unsigned short* __restrict__ W1t,
                                                  const float* __restrict__ b1,
                                                  unsigned short* __restrict__ h1b,
                                                  float* __restrict__ partial_s,
                                                  float* __restrict__ partial_ss) {
    __shared__ float red_s[256];
    __shared__ float red_ss[256];
    int tid = threadIdx.x;
    int wave = tid >> 6, lane = tid & 63;
    int quad = lane >> 4, m16 = lane & 15;
    int col0 = wave * 64;

    short8 bfr[4][4];    // [kk][f] resident weight fragments
    float bias[4];
#pragma unroll
    for (int f = 0; f < 4; ++f) {
        bias[f] = b1[col0 + f * 16 + m16];
#pragma unroll
        for (int kk = 0; kk < 4; ++kk)
            bfr[kk][f] = *(const short8*)(W1t + (col0 + f * 16 + m16) * D + kk * 32 + quad * 8);
    }
    float ps[4] = {0.f, 0.f, 0.f, 0.f}, pss[4] = {0.f, 0.f, 0.f, 0.f};

    for (int it = blockIdx.x; it < TILES; it += GRID_G) {
        int row0 = it * 16;
        const short8* aptr = (const short8*)(h0b + (row0 + m16) * D + quad * 8);
        short8 afr[4];
#pragma unroll
        for (int kk = 0; kk < 4; ++kk) afr[kk] = aptr[kk * 4];
        f32x4 acc[4];
#pragma unroll
        for (int f = 0; f < 4; ++f) acc[f] = (f32x4){0.f, 0.f, 0.f, 0.f};
#pragma unroll
        for (int kk = 0; kk < 4; ++kk)
#pragma unroll
            for (int f = 0; f < 4; ++f)
                acc[f] = __builtin_amdgcn_mfma_f32_16x16x32_bf16(afr[kk], bfr[kk][f], acc[f], 0, 0, 0);
#pragma unroll
        for (int f = 0; f < 4; ++f) {
            int col = col0 + f * 16 + m16;
#pragma unroll
            for (int r = 0; r < 4; ++r) {
                float v = acc[f][r] + bias[f];
                h1b[(row0 + quad * 4 + r) * TWO_D + col] = f2b(v);
                ps[f] += v;
                pss[f] += v * v;
            }
        }
    }
#pragma unroll
    for (int f = 0; f < 4; ++f) {
        float s = ps[f], ss = pss[f];
        s += __shfl_xor(s, 16);  s += __shfl_xor(s, 32);
        ss += __shfl_xor(ss, 16); ss += __shfl_xor(ss, 32);
        if (quad == 0) {              // each column written by exactly one lane
            red_s[col0 + f * 16 + m16] = s;
            red_ss[col0 + f * 16 + m16] = ss;
        }
    }
    __syncthreads();
    {
        int base = blockIdx.x * 256 + tid;
        partial_s[base]  = red_s[tid];    // every entry written above
        partial_ss[base] = red_ss[tid];
    }
}

// ---------------- BN reduce partials -> bnacc (64 atomics/address) ----------------
__global__ __launch_bounds__(256) void bn_reduce(const float* __restrict__ partial_s,
                                                 const float* __restrict__ partial_ss,
                                                 float* __restrict__ bnacc) {
    int c = threadIdx.x;
    float s = 0.f, ss = 0.f;
    for (int rb = blockIdx.x; rb < GRID_G; rb += 64) {
        s += partial_s[rb * 256 + c];
        ss += partial_ss[rb * 256 + c];
    }
    atomicAdd(&bnacc[c], s);
    atomicAdd(&bnacc[TWO_D + c], ss);
}

// ---------------- GEMM2 (MFMA): persistent B, M-loop; BN finalize + BN/ReLU stage + LN + mix ----------------
__global__ __launch_bounds__(256) void gemm2_mfma(const unsigned short* __restrict__ h1b,
                                                  const float* __restrict__ bnacc,
                                                  const float* __restrict__ bn_g,
                                                  const float* __restrict__ bn_b,
                                                  const unsigned short* __restrict__ W2t,
                                                  const float* __restrict__ b2,
                                                  const float* __restrict__ ln_g,
                                                  const float* __restrict__ ln_b,
                                                  const unsigned int* __restrict__ xb2,
                                                  float* __restrict__ out) {
    __shared__ float sc_s[TWO_D], sh_s[TWO_D];
    __shared__ unsigned short As[16][264];
    __shared__ float yt[16][132];
    __shared__ float mu_s[16], rstd_s[16];
    int tid = threadIdx.x;
    int wave = tid >> 6, lane = tid & 63;
    int quad = lane >> 4, m16 = lane & 15;

    {   // BN finalize per block (bnacc is 2KB, L2-resident)
        float mean = bnacc[tid] * (1.f / N_NODES);
        float var = bnacc[TWO_D + tid] * (1.f / N_NODES) - mean * mean;
        float sc = bn_g[tid] * rsqrtf(var + BN_EPS);
        sc_s[tid] = sc;
        sh_s[tid] = bn_b[tid] - mean * sc;
    }
    short8 bfr[8][2];    // resident W2t fragments
    float bias[2];
#pragma unroll
    for (int f = 0; f < 2; ++f) {
        int col = wave * 32 + f * 16 + m16;
        bias[f] = b2[col];
#pragma unroll
        for (int kk = 0; kk < 8; ++kk)
            bfr[kk][f] = *(const short8*)(W2t + col * TWO_D + kk * 32 + quad * 8);
    }
    int cp = tid & 63, rg = tid >> 6;
    float lg0 = ln_g[2 * cp], lg1 = ln_g[2 * cp + 1];
    float lb0 = ln_b[2 * cp], lb1 = ln_b[2 * cp + 1];
    int sr = tid >> 4, sc0 = (tid & 15) * 16;
    __syncthreads();

    for (int it = blockIdx.x; it < TILES; it += GRID_G) {
        int row0 = it * 16;
        {   // stage BN+ReLU'd A tile
            const unsigned short* srcp = h1b + (row0 + sr) * TWO_D + sc0;
            short8 v0 = *(const short8*)(srcp);
            short8 v1 = *(const short8*)(srcp + 8);
            short8 o0, o1;
#pragma unroll
            for (int jj = 0; jj < 8; ++jj) {
                float v = b2f((unsigned short)v0[jj]);
                v = fmaxf(v * sc_s[sc0 + jj] + sh_s[sc0 + jj], 0.f);
                o0[jj] = (short)f2b(v);
                float w = b2f((unsigned short)v1[jj]);
                w = fmaxf(w * sc_s[sc0 + 8 + jj] + sh_s[sc0 + 8 + jj], 0.f);
                o1[jj] = (short)f2b(w);
            }
            *(short8*)&As[sr][sc0] = o0;
            *(short8*)&As[sr][sc0 + 8] = o1;
        }
        __syncthreads();
        f32x4 acc[2] = {{0.f,0.f,0.f,0.f},{0.f,0.f,0.f,0.f}};
#pragma unroll
        for (int kk = 0; kk < 8; ++kk) {
            short8 a = *(const short8*)&As[m16][kk * 32 + quad * 8];
#pragma unroll
            for (int f = 0; f < 2; ++f)
                acc[f] = __builtin_amdgcn_mfma_f32_16x16x32_bf16(a, bfr[kk][f], acc[f], 0, 0, 0);
        }
#pragma unroll
        for (int f = 0; f < 2; ++f) {
            int col = wave * 32 + f * 16 + m16;
#pragma unroll
            for (int r = 0; r < 4; ++r) yt[quad * 4 + r][col] = acc[f][r] + bias[f];
        }
        __syncthreads();
        {   // LN stats: 16 threads per row
            int r = tid >> 4, lane16 = tid & 15;
            float s = 0.f, ss = 0.f;
            for (int jj = lane16; jj < D; jj += 16) {
                float v = yt[r][jj];
                s += v;
                ss += v * v;
            }
#pragma unroll
            for (int o = 1; o < 16; o <<= 1) {
                s += __shfl_xor(s, o);
                ss += __shfl_xor(ss, o);
            }
            if (lane16 == 0) {
                float mu = s * (1.f / D);
                float var = ss * (1.f / D) - mu * mu;
                mu_s[r] = mu;
                rstd_s[r] = rsqrtf(var + LN_EPS);
            }
        }
        __syncthreads();
#pragma unroll
        for (int rp = 0; rp < 4; ++rp) {
            int rl = rp * 4 + rg;
            int row = row0 + rl;
            unsigned int px = xb2[row * 64 + cp];
            float z0 = (yt[rl][2 * cp] - mu_s[rl]) * rstd_s[rl] * lg0 + lb0;
            float z1 = (yt[rl][2 * cp + 1] - mu_s[rl]) * rstd_s[rl] * lg1 + lb1;
            float o0 = 0.5f * lo_f(px) + 0.5f * fmaxf(z0, 0.f) + 0.5f * z0;
            float o1 = 0.5f * hi_f(px) + 0.5f * fmaxf(z1, 0.f) + 0.5f * z1;
            ((float2*)out)[row * 64 + cp] = make_float2(o0, o1);
        }
        __syncthreads();   // protect As/yt before next tile's staging writes
    }
}

// ---------------- launch ----------------

extern "C" void kernel_launch(void* const* d_in, const int* in_sizes, int n_in,
                              void* d_out, int out_size, void* d_ws, size_t ws_size,
                              hipStream_t stream) {
    const float* x    = (const float*)d_in[0];
    const int*   ei   = (const int*)d_in[1];
    const float* t    = (const float*)d_in[2];
    const float* W1   = (const float*)d_in[3];
    const float* b1   = (const float*)d_in[4];
    const float* bn_g = (const float*)d_in[5];
    const float* bn_b = (const float*)d_in[6];
    const float* W2   = (const float*)d_in[7];
    const float* b2   = (const float*)d_in[8];
    const float* ln_g = (const float*)d_in[9];
    const float* ln_b = (const float*)d_in[10];
    float* out = (float*)d_out;

    char* ws = (char*)d_ws;
    size_t off = 0;
    auto alloc = [&](size_t bytes) -> void* {
        void* p = ws + off;
        off = (off + bytes + 255) & ~(size_t)255;
        return p;
    };
    int*            counts     = (int*)alloc((size_t)N_NODES * 4);
    int*            offsets    = (int*)alloc((size_t)(N_NODES + 1) * 4);
    int*            rank       = (int*)alloc((size_t)N_EDGES * 4);
    int*            csr_src    = (int*)alloc((size_t)N_EDGES * 4);
    unsigned int*   xb2        = (unsigned int*)alloc((size_t)N_NODES * 64 * 4);
    unsigned int*   h0b2       = (unsigned int*)alloc((size_t)N_NODES * 64 * 4);
    unsigned short* h1b        = (unsigned short*)alloc((size_t)N_NODES * TWO_D * 2);
    unsigned short* W1t        = (unsigned short*)alloc((size_t)D * TWO_D * 2);
    unsigned short* W2t        = (unsigned short*)alloc((size_t)D * TWO_D * 2);
    float*          partial_s  = (float*)alloc((size_t)GRID_G * TWO_D * 4);
    float*          partial_ss = (float*)alloc((size_t)GRID_G * TWO_D * 4);
    float*          bnacc      = (float*)alloc(2 * TWO_D * 4);

    const int* src = ei;
    const int* dst = ei + N_EDGES;

    hipMemsetAsync(counts, 0, (size_t)N_NODES * 4, stream);
    prep_all<<<12500, 256, 0, stream>>>(x, W1, W2, dst, W1t, W2t, xb2, counts, rank, bnacc);
    scan_offsets<<<196, 256, 0, stream>>>(counts, offsets);
    scatter_kernel<<<(N_EDGES + 255) / 256, 256, 0, stream>>>(src, dst, offsets, rank, csr_src);
    agg_kernel<<<12500, 256, 0, stream>>>(xb2, offsets, csr_src, t, h0b2);
    gemm1_mfma<<<GRID_G, 256, 0, stream>>>((const unsigned short*)h0b2, W1t, b1, h1b,
                                           partial_s, partial_ss);
    bn_reduce<<<64, 256, 0, stream>>>(partial_s, partial_ss, bnacc);
    gemm2_mfma<<<GRID_G, 256, 0, stream>>>(h1b, bnacc, bn_g, bn_b, W2t, b2,
                                           ln_g, ln_b, xb2, out);
}